// Round 1
// baseline (102.956 us; speedup 1.0000x reference)
//
#include <hip/hip_runtime.h>
#include <hip/hip_bf16.h>

// Chamfer distance, p/q: (2, 64, 1024, 4) fp32; use components 1..3.
// d2(n,m) = |p3[n] - q3[m]|^2 computed as (q_sq - 2*dot) + p_sq, with the
// p_sq added AFTER the min-loop (saves 1 op/pair). sqrt is monotone so we
// min d2 first, then sqrt(max(.,0)+1e-12) once per point.
//
// Kernel 1 (chamfer_tiles): 512 blocks = 128 batches x 4 quarters.
//   Pass A: all 1024 rows (R=4/thread), reduce over the block's m-quarter
//           (256 pts staged in LDS as float4 (x,y,z,qsq); broadcast reads).
//   Pass B: symmetric, cols over the n-quarter.
//   Partial mins (+row normsq) -> workspace.
// Kernel 2 (chamfer_reduce): combine 4 partials, clamp+eps+sqrt, sum,
//   256 block-level atomicAdds into d_out.

#define QUARTS 4          // tiles per batch along the reduced axis
#define TPB 256
#define ROWS_PER_THREAD 4
#define RED_BLOCKS 256

__global__ __launch_bounds__(TPB, 2) void chamfer_tiles(
    const float4* __restrict__ P, const float4* __restrict__ Q,
    float* __restrict__ pq_part, float* __restrict__ qp_part)
{
    __shared__ float4 tile[TPB];
    const int blk   = blockIdx.x;
    const int batch = blk >> 2;      // 0..127  (c*64 + b)
    const int j     = blk & 3;       // quarter index
    const int t     = threadIdx.x;
    const int base  = batch << 10;   // batch * 1024 points

    // ---------------- Pass A: min over m-quarter, for all n ----------------
    {
        float4 v = Q[base + (j << 8) + t];
        float qsq = v.y * v.y + v.z * v.z + v.w * v.w;
        tile[t] = make_float4(v.y, v.z, v.w, qsq);
    }
    float rx[ROWS_PER_THREAD], ry[ROWS_PER_THREAD], rz[ROWS_PER_THREAD];
    float acc[ROWS_PER_THREAD];
#pragma unroll
    for (int r = 0; r < ROWS_PER_THREAD; ++r) {
        float4 v = P[base + t + (r << 8)];
        rx[r] = v.y; ry[r] = v.z; rz[r] = v.w;
        acc[r] = 3.4e38f;
    }
    __syncthreads();
#pragma unroll 4
    for (int m = 0; m < 256; ++m) {
        float4 qv = tile[m];
#pragma unroll
        for (int r = 0; r < ROWS_PER_THREAD; ++r) {
            float dot = rx[r] * qv.x + ry[r] * qv.y + rz[r] * qv.z;
            float val = fmaf(-2.0f, dot, qv.w);
            acc[r] = fminf(acc[r], val);
        }
    }
#pragma unroll
    for (int r = 0; r < ROWS_PER_THREAD; ++r) {
        float psq = rx[r] * rx[r] + ry[r] * ry[r] + rz[r] * rz[r];
        pq_part[(batch << 12) + (j << 10) + t + (r << 8)] = acc[r] + psq;
    }
    __syncthreads();   // pass-A loop done; safe to overwrite tile

    // ---------------- Pass B: min over n-quarter, for all m ----------------
    {
        float4 v = P[base + (j << 8) + t];
        float psq = v.y * v.y + v.z * v.z + v.w * v.w;
        tile[t] = make_float4(v.y, v.z, v.w, psq);
    }
#pragma unroll
    for (int r = 0; r < ROWS_PER_THREAD; ++r) {
        float4 v = Q[base + t + (r << 8)];
        rx[r] = v.y; ry[r] = v.z; rz[r] = v.w;
        acc[r] = 3.4e38f;
    }
    __syncthreads();
#pragma unroll 4
    for (int n = 0; n < 256; ++n) {
        float4 pv = tile[n];
#pragma unroll
        for (int r = 0; r < ROWS_PER_THREAD; ++r) {
            float dot = rx[r] * pv.x + ry[r] * pv.y + rz[r] * pv.z;
            float val = fmaf(-2.0f, dot, pv.w);
            acc[r] = fminf(acc[r], val);
        }
    }
#pragma unroll
    for (int r = 0; r < ROWS_PER_THREAD; ++r) {
        float qsq = rx[r] * rx[r] + ry[r] * ry[r] + rz[r] * rz[r];
        qp_part[(batch << 12) + (j << 10) + t + (r << 8)] = acc[r] + qsq;
    }
}

__global__ __launch_bounds__(TPB) void chamfer_reduce(
    const float* __restrict__ pq_part, const float* __restrict__ qp_part,
    float* __restrict__ out)
{
    __shared__ float wsum[TPB / 64];
    const int t = threadIdx.x;
    float sum = 0.0f;
    // 2 sides * 128 batches * 1024 rows = 2^18 entries
    for (int idx = blockIdx.x * TPB + t; idx < (1 << 18); idx += TPB * RED_BLOCKS) {
        const float* part = (idx < (1 << 17)) ? pq_part : qp_part;
        const int r = idx & ((1 << 17) - 1);
        const int batch = r >> 10;
        const int row = r & 1023;
        const float* pp = part + (batch << 12) + row;
        float v = fminf(fminf(pp[0], pp[1 << 10]), fminf(pp[2 << 10], pp[3 << 10]));
        sum += sqrtf(fmaxf(v, 0.0f) + 1e-12f);
    }
#pragma unroll
    for (int off = 32; off; off >>= 1) sum += __shfl_down(sum, off, 64);
    if ((t & 63) == 0) wsum[t >> 6] = sum;
    __syncthreads();
    if (t == 0) {
        float s = wsum[0] + wsum[1] + wsum[2] + wsum[3];
        atomicAdd(out, s);
    }
}

extern "C" void kernel_launch(void* const* d_in, const int* in_sizes, int n_in,
                              void* d_out, int out_size, void* d_ws, size_t ws_size,
                              hipStream_t stream) {
    const float4* P = (const float4*)d_in[0];
    const float4* Q = (const float4*)d_in[1];
    float* out = (float*)d_out;
    float* pq_part = (float*)d_ws;               // 128*4*1024 floats = 2 MB
    float* qp_part = pq_part + (1 << 19);        // another 2 MB

    hipMemsetAsync(d_out, 0, sizeof(float), stream);
    chamfer_tiles<<<dim3(128 * QUARTS), dim3(TPB), 0, stream>>>(P, Q, pq_part, qp_part);
    chamfer_reduce<<<dim3(RED_BLOCKS), dim3(TPB), 0, stream>>>(pq_part, qp_part, out);
}